// Round 1
// 1563.744 us; speedup vs baseline: 1.0666x; 1.0666x over previous
//
#include <hip/hip_runtime.h>
#include <hip/hip_bf16.h>

// Problem constants (B, C, H, W) = (8, 1024, 64, 64); N = H*W = 4096.
#define BATCH 8
#define CH    1024
#define NN    4096

typedef __attribute__((ext_vector_type(8))) short bf16x8;   // 8 bf16 = 4 VGPRs
typedef __attribute__((ext_vector_type(4))) float f32x4;
using bf16 = __hip_bfloat16;

struct bhalf4 { bf16 x, y, z, w; };               // 8 bytes

// ---------------------------------------------------------------------------
// Transpose + cast, batched over z: in [B][C][N] fp32 -> out [B][N][C] bf16.
// ASQ variant also accumulates a_sq[b][n] = sum_c in[b][c][n]^2 (fp32).
// ---------------------------------------------------------------------------
template <bool ASQ>
__global__ __launch_bounds__(256) void transpose_cast_b(
    const float* __restrict__ in_all, bf16* __restrict__ out_all,
    float* __restrict__ asq_all) {
  int bz = blockIdx.z;
  const float* in = in_all + (size_t)bz * CH * NN;
  bf16* out = out_all + (size_t)bz * NN * CH;

  __shared__ float tile[32][33];                            // +1 pad: no bank conflicts
  int n0 = blockIdx.x * 32;
  int c0 = blockIdx.y * 32;
  int tx = threadIdx.x;   // 0..31
  int ty = threadIdx.y;   // 0..7

  float sq = 0.f;
#pragma unroll
  for (int i = 0; i < 4; ++i) {
    int c = c0 + ty + i * 8;
    float v = in[(size_t)c * NN + n0 + tx];
    tile[ty + i * 8][tx] = v;
    if (ASQ) sq += v * v;
  }
  if (ASQ) atomicAdd(&asq_all[(size_t)bz * NN + n0 + tx], sq);
  __syncthreads();
#pragma unroll
  for (int i = 0; i < 4; ++i) {
    int n = n0 + ty + i * 8;
    out[(size_t)n * CH + c0 + tx] = __float2bfloat16(tile[tx][ty + i * 8]);
  }
}

// ---------------------------------------------------------------------------
// Plain cast: [B*C*N] fp32 -> bf16 flat (mo is already K-contiguous).
// ---------------------------------------------------------------------------
__global__ __launch_bounds__(256) void convert_cast(
    const float4* __restrict__ in, bhalf4* __restrict__ out) {
  size_t i = (size_t)blockIdx.x * 256 + threadIdx.x;
  float4 v = in[i];
  bhalf4 o;
  o.x = __float2bfloat16(v.x);
  o.y = __float2bfloat16(v.y);
  o.z = __float2bfloat16(v.z);
  o.w = __float2bfloat16(v.w);
  out[i] = o;
}

// ---------------------------------------------------------------------------
// 256x256 / BK=64 8-phase counted-vmcnt GEMM (C = A * B^T), both inputs
// row-major [rows][K] bf16. 8 waves (2Mx4N), per-wave 128x64 output.
// LDS 128 KiB: As[2][256][64] + Bs[2][256][64], XOR-swizzle chunk^=(row&7)
// applied by pre-swizzling the *global* source of global_load_lds (LDS dest
// stays linear) and applying the same XOR on the ds_read side.
//
// Phase schedule per K-tile t (buffers: cur = t&1):
//   ph0: ds_read A m0-3, B n0-1 (12);  stage A(t+1,half0);  MFMA m0-3 x n0-1
//   ph1: ds_read B n2-3 (4);           stage A(t+1,half1);  MFMA m0-3 x n2-3
//   ph2: ds_read A m4-7 (8);           stage B(t+2,half0);  MFMA m4-7 x n2-3
//   ph3:                               stage B(t+2,half1);  MFMA m4-7 x n0-1
//        then s_waitcnt vmcnt(4) (drain older loads; t+2's B stays in flight)
// Race-freedom: every phase's ds_reads are drained by its lgkmcnt(0) before
// its trailing barrier; staging into a region is only issued after the
// barrier that follows the last read of that region. Tail: vmcnt(0).
//
// MODE 0 (gemm1): epilogue e=exp((2*acc-asq[n])/32) -> P bf16, rowsum atomics.
// MODE 1 (gemm2): epilogue acc/rowsum[n] -> fp32 out.
// GY = M/256 tiles; N is always 4096 (16 tiles); grid = 16*GY*BATCH linear,
// XCD-bijective swizzle (nwg % 8 == 0 in both cases).
// ---------------------------------------------------------------------------
template <int K, int MODE, int GY>
__global__ __launch_bounds__(512, 2) void gemm_8p(
    const bf16* __restrict__ Aall, const bf16* __restrict__ Ball,
    bf16* __restrict__ Pall, float* __restrict__ Oall,
    const float* __restrict__ asq_all, float* __restrict__ rsum_all) {
  constexpr int NT = K / 64;
  constexpr int NWG = 16 * GY * BATCH;

  // XCD-aware swizzle: consecutive hardware ids on one XCD get a contiguous
  // tile chunk (one batch per XCD here: NWG/8 = tiles per batch).
  int lid = blockIdx.x;
  int swz = (lid & 7) * (NWG >> 3) + (lid >> 3);
  int bz  = swz / (16 * GY);
  int rem = swz - bz * (16 * GY);
  int by = rem >> 4;          // M tile
  int bx = rem & 15;          // N tile

  const bf16* Ab = Aall + (size_t)bz * 4096 * 1024 + (size_t)(by * 256) * K;
  const bf16* Bb = Ball + (size_t)bz * 4096 * (size_t)K + (size_t)(bx * 256) * K;

  __shared__ bf16 As[2][256 * 64];
  __shared__ bf16 Bs[2][256 * 64];

  int tid = threadIdx.x;
  int wv = tid >> 6, lane = tid & 63;
  int fl = lane & 15, quad = lane >> 4;
  int wr = wv >> 2, wc = wv & 3;          // wave -> (2M x 4N) sub-tile

  // Staging: per half-tile (128 rows x 64 cols) each thread does 2 x 16B.
  // cid = j*512 + tid; row = cid>>3 (within half), chunk = (cid&7) ^ (row&7).
  int r0 = tid >> 3;
  int c0 = (tid & 7) ^ (r0 & 7);
  int r1 = (512 + tid) >> 3;
  int c1 = ((512 + tid) & 7) ^ (r1 & 7);
  size_t ga0 = (size_t)r0 * K + c0 * 8;   // element offset in global half-panel
  size_t ga1 = (size_t)r1 * K + c1 * 8;
  int ls0 = wv * 512;                     // LDS element offset (wave-uniform)
  int ls1 = 4096 + wv * 512;

#define STAGE(MAT, BUF, T, HF) do { if ((T) < NT) {                            \
    const bf16* g_ = (MAT) + (size_t)(HF) * 128 * K + (size_t)(T) * 64;        \
    bf16* d_ = &BUF[(T) & 1][(HF) * 8192];                                     \
    __builtin_amdgcn_global_load_lds(                                          \
        (const __attribute__((address_space(1))) void*)(g_ + ga0),             \
        (__attribute__((address_space(3))) void*)(d_ + ls0), 16, 0, 0);        \
    __builtin_amdgcn_global_load_lds(                                          \
        (const __attribute__((address_space(1))) void*)(g_ + ga1),             \
        (__attribute__((address_space(3))) void*)(d_ + ls1), 16, 0, 0);        \
  } } while (0)

  f32x4 acc[8][4] = {};

  // Prologue: stream order per tile is (B0,B1,A0,A1); A of tile1 is staged
  // inside tile0's ph0/ph1. 12 loads issued, wait all but tile1's B (4).
  STAGE(Bb, Bs, 0, 0);
  STAGE(Bb, Bs, 0, 1);
  STAGE(Ab, As, 0, 0);
  STAGE(Ab, As, 0, 1);
  STAGE(Bb, Bs, 1, 0);
  STAGE(Bb, Bs, 1, 1);
  asm volatile("s_waitcnt vmcnt(4)" ::: "memory");
  __builtin_amdgcn_s_barrier();

  for (int t = 0; t < NT; ++t) {
    const bf16* Ac = As[t & 1];
    const bf16* Bc = Bs[t & 1];
    bf16x8 aL[4][2], aH[4][2], bF[4][2];

    // ---- phase 0: read A m0-3 + B n0-1; stage A(t+1, half0) ----
#pragma unroll
    for (int mi = 0; mi < 4; ++mi)
#pragma unroll
      for (int ks = 0; ks < 2; ++ks) {
        int r = wr * 128 + mi * 16 + fl;
        aL[mi][ks] = *(const bf16x8*)(Ac + r * 64 + (((ks << 2) | quad) ^ (r & 7)) * 8);
      }
#pragma unroll
    for (int nj = 0; nj < 2; ++nj)
#pragma unroll
      for (int ks = 0; ks < 2; ++ks) {
        int r = wc * 64 + nj * 16 + fl;
        bF[nj][ks] = *(const bf16x8*)(Bc + r * 64 + (((ks << 2) | quad) ^ (r & 7)) * 8);
      }
    STAGE(Ab, As, t + 1, 0);
    __builtin_amdgcn_s_barrier();
    asm volatile("s_waitcnt lgkmcnt(0)" ::: "memory");
    __builtin_amdgcn_s_setprio(1);
#pragma unroll
    for (int mi = 0; mi < 4; ++mi)
#pragma unroll
      for (int nj = 0; nj < 2; ++nj)
#pragma unroll
        for (int ks = 0; ks < 2; ++ks)
          acc[mi][nj] = __builtin_amdgcn_mfma_f32_16x16x32_bf16(
              aL[mi][ks], bF[nj][ks], acc[mi][nj], 0, 0, 0);
    __builtin_amdgcn_s_setprio(0);
    __builtin_amdgcn_s_barrier();

    // ---- phase 1: read B n2-3; stage A(t+1, half1) ----
#pragma unroll
    for (int nj = 2; nj < 4; ++nj)
#pragma unroll
      for (int ks = 0; ks < 2; ++ks) {
        int r = wc * 64 + nj * 16 + fl;
        bF[nj][ks] = *(const bf16x8*)(Bc + r * 64 + (((ks << 2) | quad) ^ (r & 7)) * 8);
      }
    STAGE(Ab, As, t + 1, 1);
    __builtin_amdgcn_s_barrier();
    asm volatile("s_waitcnt lgkmcnt(0)" ::: "memory");
    __builtin_amdgcn_s_setprio(1);
#pragma unroll
    for (int mi = 0; mi < 4; ++mi)
#pragma unroll
      for (int nj = 2; nj < 4; ++nj)
#pragma unroll
        for (int ks = 0; ks < 2; ++ks)
          acc[mi][nj] = __builtin_amdgcn_mfma_f32_16x16x32_bf16(
              aL[mi][ks], bF[nj][ks], acc[mi][nj], 0, 0, 0);
    __builtin_amdgcn_s_setprio(0);
    __builtin_amdgcn_s_barrier();

    // ---- phase 2: read A m4-7; stage B(t+2, half0) ----
    // (all B reads of this tile drained at phase-1's lgkmcnt -> safe to
    //  start overwriting buffer cur's B region with tile t+2 data)
#pragma unroll
    for (int mi = 0; mi < 4; ++mi)
#pragma unroll
      for (int ks = 0; ks < 2; ++ks) {
        int r = wr * 128 + (mi + 4) * 16 + fl;
        aH[mi][ks] = *(const bf16x8*)(Ac + r * 64 + (((ks << 2) | quad) ^ (r & 7)) * 8);
      }
    STAGE(Bb, Bs, t + 2, 0);
    __builtin_amdgcn_s_barrier();
    asm volatile("s_waitcnt lgkmcnt(0)" ::: "memory");
    __builtin_amdgcn_s_setprio(1);
#pragma unroll
    for (int mi = 0; mi < 4; ++mi)
#pragma unroll
      for (int nj = 2; nj < 4; ++nj)
#pragma unroll
        for (int ks = 0; ks < 2; ++ks)
          acc[mi + 4][nj] = __builtin_amdgcn_mfma_f32_16x16x32_bf16(
              aH[mi][ks], bF[nj][ks], acc[mi + 4][nj], 0, 0, 0);
    __builtin_amdgcn_s_setprio(0);
    __builtin_amdgcn_s_barrier();

    // ---- phase 3: stage B(t+2, half1); MFMA m4-7 x n0-1; counted vmcnt ----
    STAGE(Bb, Bs, t + 2, 1);
    __builtin_amdgcn_s_barrier();
    __builtin_amdgcn_s_setprio(1);
#pragma unroll
    for (int mi = 0; mi < 4; ++mi)
#pragma unroll
      for (int nj = 0; nj < 2; ++nj)
#pragma unroll
        for (int ks = 0; ks < 2; ++ks)
          acc[mi + 4][nj] = __builtin_amdgcn_mfma_f32_16x16x32_bf16(
              aH[mi][ks], bF[nj][ks], acc[mi + 4][nj], 0, 0, 0);
    __builtin_amdgcn_s_setprio(0);
    // Steady state: the 4 youngest loads are B(t+2,*) which tile t+1 does not
    // read; everything older (incl. A(t+1,*)) must have landed. When B(t+2)
    // was skipped (tail), the youngest are A(t+1,*) themselves -> drain to 0.
    if (t + 2 < NT) {
      asm volatile("s_waitcnt vmcnt(4)" ::: "memory");
    } else {
      asm volatile("s_waitcnt vmcnt(0)" ::: "memory");
    }
    __builtin_amdgcn_s_barrier();
  }
#undef STAGE

  // ---- Epilogue ----
  if constexpr (MODE == 0) {
    const float* asq = asq_all + (size_t)bz * NN;
    float* rsum = rsum_all + (size_t)bz * NN;
    bf16* P = Pall + (size_t)bz * NN * NN;
    float rs[8][4];
#pragma unroll
    for (int mi = 0; mi < 8; ++mi)
#pragma unroll
      for (int r = 0; r < 4; ++r) rs[mi][r] = 0.f;
#pragma unroll
    for (int nj = 0; nj < 4; ++nj) {
      int col = bx * 256 + wc * 64 + nj * 16 + fl;
      float aq = asq[col];
#pragma unroll
      for (int mi = 0; mi < 8; ++mi)
#pragma unroll
        for (int r = 0; r < 4; ++r) {
          int row = by * 256 + wr * 128 + mi * 16 + (quad << 2) + r;
          float e = __expf((2.f * acc[mi][nj][r] - aq) * 0.03125f);
          P[(size_t)row * NN + col] = __float2bfloat16(e);
          rs[mi][r] += e;
        }
    }
#pragma unroll
    for (int mi = 0; mi < 8; ++mi)
#pragma unroll
      for (int r = 0; r < 4; ++r) {
        float v = rs[mi][r];
        v += __shfl_xor(v, 1);
        v += __shfl_xor(v, 2);
        v += __shfl_xor(v, 4);
        v += __shfl_xor(v, 8);
        if (fl == 0)
          atomicAdd(&rsum[by * 256 + wr * 128 + mi * 16 + (quad << 2) + r], v);
      }
  } else {
    float* Co = Oall + (size_t)bz * 2 * CH * NN;     // first CV block
    const float* rsum = rsum_all + (size_t)bz * NN;
#pragma unroll
    for (int nj = 0; nj < 4; ++nj) {
      int col = bx * 256 + wc * 64 + nj * 16 + fl;
      float inv = 1.f / rsum[col];
#pragma unroll
      for (int mi = 0; mi < 8; ++mi)
#pragma unroll
        for (int r = 0; r < 4; ++r) {
          int row = by * 256 + wr * 128 + mi * 16 + (quad << 2) + r;
          Co[(size_t)row * NN + col] = acc[mi][nj][r] * inv;
        }
    }
  }
}

// ---------------------------------------------------------------------------
// Copy curr_value into the second half of each batch's output channel block.
// ---------------------------------------------------------------------------
__global__ __launch_bounds__(256) void copy_curr(
    const float4* __restrict__ src, float4* __restrict__ dst) {
  size_t idx = (size_t)blockIdx.x * 256 + threadIdx.x;
  size_t b = idx >> 20;                                  // / (1024*4096/4)
  size_t r = idx & 1048575;
  dst[b * 2097152 + 1048576 + r] = src[idx];
}

// ---------------------------------------------------------------------------
extern "C" void kernel_launch(void* const* d_in, const int* in_sizes, int n_in,
                              void* d_out, int out_size, void* d_ws, size_t ws_size,
                              hipStream_t stream) {
  const float* prev_key   = (const float*)d_in[0];
  const float* prev_value = (const float*)d_in[1];
  const float* curr_key   = (const float*)d_in[2];
  const float* curr_value = (const float*)d_in[3];
  float* out = (float*)d_out;

  char* ws = (char*)d_ws;
  // Layout: total used = 448.25 MB
  bf16* P     = (bf16*)(ws);                        // 256 MB [B][N][N]
  bf16* mk_t  = (bf16*)(ws + 268435456u);           //  64 MB [B][N][C]
  bf16* qk_t  = (bf16*)(ws + 335544320u);           //  64 MB [B][N][C]
  bf16* mo_b  = (bf16*)(ws + 402653184u);           //  64 MB [B][C][N]
  float* a_sq = (float*)(ws + 469762048u);          // 128 KB [B][N]
  float* rsum = a_sq + (size_t)BATCH * NN;          // 128 KB [B][N]

  // Zero a_sq + rowsum (contiguous 256 KB).
  hipMemsetAsync(a_sq, 0, 2ull * BATCH * NN * sizeof(float), stream);

  transpose_cast_b<true><<<dim3(NN / 32, CH / 32, BATCH), dim3(32, 8), 0, stream>>>(
      prev_key, mk_t, a_sq);
  transpose_cast_b<false><<<dim3(NN / 32, CH / 32, BATCH), dim3(32, 8), 0, stream>>>(
      curr_key, qk_t, nullptr);
  convert_cast<<<(size_t)BATCH * CH * NN / 4 / 256, 256, 0, stream>>>(
      (const float4*)prev_value, (bhalf4*)mo_b);

  // GEMM1: ab = qk_t * mk_t^T  (M=N=4096, K=1024), fused exp + rowsum.
  gemm_8p<CH, 0, 16><<<dim3(16 * 16 * BATCH), dim3(512), 0, stream>>>(
      qk_t, mk_t, P, nullptr, a_sq, rsum);

  // GEMM2: mem = mo * P^T  (M=1024, N=4096, K=4096), fused 1/rowsum.
  gemm_8p<NN, 1, 4><<<dim3(16 * 4 * BATCH), dim3(512), 0, stream>>>(
      mo_b, P, nullptr, out, nullptr, rsum);

  copy_curr<<<(size_t)BATCH * CH * NN / 4 / 256, 256, 0, stream>>>(
      (const float4*)curr_value, (float4*)out);
}

// Round 5
// 1431.415 us; speedup vs baseline: 1.1652x; 1.0924x over previous
//
#include <hip/hip_runtime.h>
#include <hip/hip_bf16.h>

// Problem constants (B, C, H, W) = (8, 1024, 64, 64); N = H*W = 4096.
#define BATCH 8
#define CH    1024
#define NN    4096

typedef __attribute__((ext_vector_type(8))) short bf16x8;   // 8 bf16 = 4 VGPRs
typedef __attribute__((ext_vector_type(4))) float f32x4;
using bf16 = __hip_bfloat16;

struct bhalf4 { bf16 x, y, z, w; };               // 8 bytes

__device__ __forceinline__ unsigned short f2bfu(float f) {
  bf16 h = __float2bfloat16(f);
  return *reinterpret_cast<unsigned short*>(&h);
}

// ---------------------------------------------------------------------------
// Vectorized transpose + cast: in [B][C][N] fp32 -> out [B][N][C] bf16.
// 64x64 tile, float4 loads, ushort8 stores. ASQ: asq[b][n] += sum_c in^2.
// (Write/read phases separated by __syncthreads — ordering is safe here.)
// ---------------------------------------------------------------------------
template <bool ASQ>
__global__ __launch_bounds__(256) void transpose_cast_v(
    const float* __restrict__ in_all, bf16* __restrict__ out_all,
    float* __restrict__ asq_all) {
  int bz = blockIdx.z;
  const float* in = in_all + (size_t)bz * CH * NN;
  bf16* out = out_all + (size_t)bz * NN * CH;

  __shared__ float tile[64][65];        // +1 pad: conflict-free both sides
  __shared__ float sqb[16][64];

  int n0 = blockIdx.x * 64;
  int c0 = blockIdx.y * 64;
  int t = threadIdx.x;
  int nc = t & 15;        // n-chunk (float4)
  int cr = t >> 4;        // 0..15

  float4 sq4 = make_float4(0.f, 0.f, 0.f, 0.f);
#pragma unroll
  for (int i = 0; i < 4; ++i) {
    int c = cr + i * 16;
    float4 v = *(const float4*)(in + (size_t)(c0 + c) * NN + n0 + nc * 4);
    tile[c][nc * 4 + 0] = v.x;
    tile[c][nc * 4 + 1] = v.y;
    tile[c][nc * 4 + 2] = v.z;
    tile[c][nc * 4 + 3] = v.w;
    if (ASQ) {
      sq4.x += v.x * v.x; sq4.y += v.y * v.y;
      sq4.z += v.z * v.z; sq4.w += v.w * v.w;
    }
  }
  if (ASQ) {
    sqb[cr][nc * 4 + 0] = sq4.x;
    sqb[cr][nc * 4 + 1] = sq4.y;
    sqb[cr][nc * 4 + 2] = sq4.z;
    sqb[cr][nc * 4 + 3] = sq4.w;
  }
  __syncthreads();
  if (ASQ && t < 64) {
    float s = 0.f;
#pragma unroll
    for (int i = 0; i < 16; ++i) s += sqb[i][t];
    atomicAdd(&asq_all[(size_t)bz * NN + n0 + t], s);
  }
  int cchunk = t & 7;
  int nb = t >> 3;        // 0..31
#pragma unroll
  for (int p = 0; p < 2; ++p) {
    int n = nb + p * 32;
    bf16x8 o;
#pragma unroll
    for (int j = 0; j < 8; ++j)
      o[j] = (short)f2bfu(tile[cchunk * 8 + j][n]);
    *(bf16x8*)(out + (size_t)(n0 + n) * CH + c0 + cchunk * 8) = o;
  }
}

// ---------------------------------------------------------------------------
// Plain cast: [B*C*N] fp32 -> bf16 flat (mo is already K-contiguous).
// ---------------------------------------------------------------------------
__global__ __launch_bounds__(256) void convert_cast(
    const float4* __restrict__ in, bhalf4* __restrict__ out) {
  size_t i = (size_t)blockIdx.x * 256 + threadIdx.x;
  float4 v = in[i];
  bhalf4 o;
  o.x = __float2bfloat16(v.x);
  o.y = __float2bfloat16(v.y);
  o.z = __float2bfloat16(v.z);
  o.w = __float2bfloat16(v.w);
  out[i] = o;
}

// ---------------------------------------------------------------------------
// 256x256 / BK=64 GEMM (C = A * B^T), both inputs row-major [rows][K] bf16.
// 8 waves (2Mx4N), per-wave 128x64 output. LDS 128 KiB, XOR-swizzle
// chunk ^= (row&7) via pre-swizzled global source (LDS dest linear).
//
// LOOP = round-1 proven-passing schedule: 4 phases per K-tile, each phase
// {reads for THIS phase's MFMA + stage; barrier; lgkmcnt(0); sched_barrier;
// MFMA; barrier}. Counted vmcnt(4) once per K-tile keeps the next B-tile's
// loads in flight across the barrier; tail drains to 0.
//
// EPILOGUE: per-wave 16x64 XOR-swizzled LDS transpose of each 16-row
// accumulator stripe -> full 16B coalesced global stores. ROUND-5 FIX:
// the within-wave cross-lane LDS transpose now has an explicit ordering
// point (s_waitcnt lgkmcnt(0) + "memory" clobber + sched_barrier) between
// the scalar ds_writes and the vector ds_reads, and a memory fence after
// the reads. Without it the compiler may hoist the (differently-typed)
// vector reads above the scalar writes -- ds ops ARE memory ops, so the
// clobber orders them (unlike MFMA, rule #18). Scratch writes also go
// through short* so write/read element TBAA match.
//
// MODE 0 (gemm1): e = exp((2*acc - asq[n])/32) -> P bf16 + rowsum atomics.
// MODE 1 (gemm2): acc / rowsum[n] -> fp32 out.
// ---------------------------------------------------------------------------
#define BARR() __builtin_amdgcn_s_barrier()
#define PRIO(x) __builtin_amdgcn_s_setprio(x)
#define LDS_FENCE() do {                                      \
    asm volatile("s_waitcnt lgkmcnt(0)" ::: "memory");        \
    __builtin_amdgcn_sched_barrier(0);                        \
  } while (0)
#define MEM_FENCE() do {                                      \
    asm volatile("" ::: "memory");                            \
    __builtin_amdgcn_sched_barrier(0);                        \
  } while (0)

template <int K, int MODE, int GY>
__global__ __launch_bounds__(512, 2) void gemm_8p(
    const bf16* __restrict__ Aall, const bf16* __restrict__ Ball,
    bf16* __restrict__ Pall, float* __restrict__ Oall,
    const float* __restrict__ asq_all, float* __restrict__ rsum_all) {
  constexpr int NT = K / 64;
  constexpr int NWG = 16 * GY * BATCH;

  // XCD-aware bijective swizzle (NWG % 8 == 0).
  int lid = blockIdx.x;
  int swz = (lid & 7) * (NWG >> 3) + (lid >> 3);
  int bz  = swz / (16 * GY);
  int rem = swz - bz * (16 * GY);
  int by = rem >> 4;          // M tile
  int bx = rem & 15;          // N tile

  const bf16* Ab = Aall + (size_t)bz * 4096 * 1024 + (size_t)(by * 256) * K;
  const bf16* Bb = Ball + (size_t)bz * 4096 * (size_t)K + (size_t)(bx * 256) * K;

  __shared__ bf16 As[2][256 * 64];
  __shared__ bf16 Bs[2][256 * 64];

  int tid = threadIdx.x;
  int wv = tid >> 6, lane = tid & 63;
  int fl = lane & 15, quad = lane >> 4;
  int wr = wv >> 2, wc = wv & 3;          // wave -> (2M x 4N) sub-tile

  // Staging: per half-tile (128 rows x 64 cols) each thread does 2 x 16B.
  int r0 = tid >> 3;
  int c0 = (tid & 7) ^ (r0 & 7);
  int r1 = (512 + tid) >> 3;
  int c1 = ((512 + tid) & 7) ^ (r1 & 7);
  size_t ga0 = (size_t)r0 * K + c0 * 8;   // element offset in global half-panel
  size_t ga1 = (size_t)r1 * K + c1 * 8;
  int ls0 = wv * 512;                     // LDS element offset (wave-uniform)
  int ls1 = 4096 + wv * 512;

#define STAGE(MAT, BUF, T, HF) do { if ((T) < NT) {                            \
    const bf16* g_ = (MAT) + (size_t)(HF) * 128 * K + (size_t)(T) * 64;        \
    bf16* d_ = &BUF[(T) & 1][(HF) * 8192];                                     \
    __builtin_amdgcn_global_load_lds(                                          \
        (const __attribute__((address_space(1))) void*)(g_ + ga0),             \
        (__attribute__((address_space(3))) void*)(d_ + ls0), 16, 0, 0);        \
    __builtin_amdgcn_global_load_lds(                                          \
        (const __attribute__((address_space(1))) void*)(g_ + ga1),             \
        (__attribute__((address_space(3))) void*)(d_ + ls1), 16, 0, 0);        \
  } } while (0)

  // Fragment-read offsets: r&7 == fl&7 for all fragment rows.
  int flq = fl & 7;
  int k0 = ((0 | quad) ^ flq) * 8;
  int k1 = ((4 | quad) ^ flq) * 8;
  const int rA = wr * 128 + fl;
  const int rB = wc * 64 + fl;

  f32x4 acc[8][4] = {};
  bf16x8 aL[4][2], aH[4][2], bF[4][2];

  // Prologue: stream order (B0,A0,B1); vmcnt(4) drains tile 0 (A0+B0),
  // leaves B1's 4 loads in flight.
  STAGE(Bb, Bs, 0, 0);
  STAGE(Bb, Bs, 0, 1);
  STAGE(Ab, As, 0, 0);
  STAGE(Ab, As, 0, 1);
  STAGE(Bb, Bs, 1, 0);
  STAGE(Bb, Bs, 1, 1);
  asm volatile("s_waitcnt vmcnt(4)" ::: "memory");
  BARR();

  for (int t = 0; t < NT; ++t) {
    const bf16* Ac = As[t & 1];
    const bf16* Bc = Bs[t & 1];

    // ---- phase 0: read A m0-3 + B n0-1; stage A(t+1, h0) ----
#pragma unroll
    for (int mi = 0; mi < 4; ++mi) {
      const bf16* p = Ac + (rA + mi * 16) * 64;
      aL[mi][0] = *(const bf16x8*)(p + k0);
      aL[mi][1] = *(const bf16x8*)(p + k1);
    }
#pragma unroll
    for (int nj = 0; nj < 2; ++nj) {
      const bf16* p = Bc + (rB + nj * 16) * 64;
      bF[nj][0] = *(const bf16x8*)(p + k0);
      bF[nj][1] = *(const bf16x8*)(p + k1);
    }
    STAGE(Ab, As, t + 1, 0);
    BARR();
    asm volatile("s_waitcnt lgkmcnt(0)" ::: "memory");
    __builtin_amdgcn_sched_barrier(0);
    PRIO(1);
#pragma unroll
    for (int mi = 0; mi < 4; ++mi)
#pragma unroll
      for (int nj = 0; nj < 2; ++nj)
#pragma unroll
        for (int ks = 0; ks < 2; ++ks)
          acc[mi][nj] = __builtin_amdgcn_mfma_f32_16x16x32_bf16(
              aL[mi][ks], bF[nj][ks], acc[mi][nj], 0, 0, 0);
    PRIO(0);
    BARR();

    // ---- phase 1: read B n2-3; stage A(t+1, h1) ----
#pragma unroll
    for (int nj = 2; nj < 4; ++nj) {
      const bf16* p = Bc + (rB + nj * 16) * 64;
      bF[nj][0] = *(const bf16x8*)(p + k0);
      bF[nj][1] = *(const bf16x8*)(p + k1);
    }
    STAGE(Ab, As, t + 1, 1);
    BARR();
    asm volatile("s_waitcnt lgkmcnt(0)" ::: "memory");
    __builtin_amdgcn_sched_barrier(0);
    PRIO(1);
#pragma unroll
    for (int mi = 0; mi < 4; ++mi)
#pragma unroll
      for (int nj = 2; nj < 4; ++nj)
#pragma unroll
        for (int ks = 0; ks < 2; ++ks)
          acc[mi][nj] = __builtin_amdgcn_mfma_f32_16x16x32_bf16(
              aL[mi][ks], bF[nj][ks], acc[mi][nj], 0, 0, 0);
    PRIO(0);
    BARR();

    // ---- phase 2: read A m4-7; stage B(t+2, h0) ----
#pragma unroll
    for (int mi = 0; mi < 4; ++mi) {
      const bf16* p = Ac + (rA + 64 + mi * 16) * 64;
      aH[mi][0] = *(const bf16x8*)(p + k0);
      aH[mi][1] = *(const bf16x8*)(p + k1);
    }
    STAGE(Bb, Bs, t + 2, 0);
    BARR();
    asm volatile("s_waitcnt lgkmcnt(0)" ::: "memory");
    __builtin_amdgcn_sched_barrier(0);
    PRIO(1);
#pragma unroll
    for (int mi = 0; mi < 4; ++mi)
#pragma unroll
      for (int nj = 2; nj < 4; ++nj)
#pragma unroll
        for (int ks = 0; ks < 2; ++ks)
          acc[mi + 4][nj] = __builtin_amdgcn_mfma_f32_16x16x32_bf16(
              aH[mi][ks], bF[nj][ks], acc[mi + 4][nj], 0, 0, 0);
    PRIO(0);
    BARR();

    // ---- phase 3: stage B(t+2, h1); MFMA m4-7 x n0-1; counted vmcnt ----
    STAGE(Bb, Bs, t + 2, 1);
    BARR();
    PRIO(1);
#pragma unroll
    for (int mi = 0; mi < 4; ++mi)
#pragma unroll
      for (int nj = 0; nj < 2; ++nj)
#pragma unroll
        for (int ks = 0; ks < 2; ++ks)
          acc[mi + 4][nj] = __builtin_amdgcn_mfma_f32_16x16x32_bf16(
              aH[mi][ks], bF[nj][ks], acc[mi + 4][nj], 0, 0, 0);
    PRIO(0);
    if (t + 2 < NT) {
      asm volatile("s_waitcnt vmcnt(4)" ::: "memory");
    } else {
      asm volatile("s_waitcnt vmcnt(0)" ::: "memory");
    }
    BARR();
  }
#undef STAGE

  // All loop LDS reads drained (per-phase lgkm0) and all staging vm-drained
  // (tail vmcnt(0)); sync before reusing LDS as epilogue scratch.
  __syncthreads();

  // ---- Epilogue: wave-private LDS transpose -> coalesced 16B stores ----
  int colbase = bx * 256 + wc * 64;
  int rowg0 = by * 256 + wr * 128;

  if constexpr (MODE == 0) {
    const float* asq = asq_all + (size_t)bz * NN;
    float* rsum = rsum_all + (size_t)bz * NN;
    bf16* P = Pall + (size_t)bz * NN * NN;
    short* scr = (short*)(&As[0][0]) + wv * 1024;   // 16x64 bf16 per wave

    float aq[4];
#pragma unroll
    for (int nj = 0; nj < 4; ++nj) aq[nj] = asq[colbase + nj * 16 + fl];

    float rs[8][4];
#pragma unroll
    for (int mi = 0; mi < 8; ++mi)
#pragma unroll
      for (int r = 0; r < 4; ++r) rs[mi][r] = 0.f;

#pragma unroll
    for (int mi = 0; mi < 8; ++mi) {
      // write phase (scalar, swizzled)
#pragma unroll
      for (int nj = 0; nj < 4; ++nj)
#pragma unroll
        for (int r = 0; r < 4; ++r) {
          int row = (quad << 2) + r;
          float e = __expf((2.f * acc[mi][nj][r] - aq[nj]) * 0.03125f);
          rs[mi][r] += e;
          int chunk = (nj * 2 + (fl >> 3)) ^ (row & 7);
          scr[row * 64 + chunk * 8 + (fl & 7)] = (short)f2bfu(e);
        }
      // ORDER: ds_writes must complete & be visible before cross-lane reads.
      LDS_FENCE();
      // read phase (vector, unswizzled rows) -> coalesced stores
#pragma unroll
      for (int p = 0; p < 2; ++p) {
        int row = (p << 3) + (lane >> 3);
        int c = lane & 7;
        int chunk = c ^ (row & 7);
        bf16x8 v = *(const bf16x8*)(scr + row * 64 + chunk * 8);
        *(bf16x8*)(P + (size_t)(rowg0 + mi * 16 + row) * NN + colbase + c * 8) = v;
      }
      // Keep next stripe's writes from hoisting above these reads.
      MEM_FENCE();
    }
#pragma unroll
    for (int mi = 0; mi < 8; ++mi)
#pragma unroll
      for (int r = 0; r < 4; ++r) {
        float v = rs[mi][r];
        v += __shfl_xor(v, 1);
        v += __shfl_xor(v, 2);
        v += __shfl_xor(v, 4);
        v += __shfl_xor(v, 8);
        if (fl == 0)
          atomicAdd(&rsum[rowg0 + mi * 16 + (quad << 2) + r], v);
      }
  } else {
    float* Co = Oall + (size_t)bz * 2 * CH * NN;     // first CV block
    const float* rsum = rsum_all + (size_t)bz * NN;
    float* scr = (float*)(&As[0][0]) + wv * 1024;    // 16x64 f32 per wave

    float inv[4];
#pragma unroll
    for (int nj = 0; nj < 4; ++nj) inv[nj] = 1.f / rsum[colbase + nj * 16 + fl];

#pragma unroll
    for (int mi = 0; mi < 8; ++mi) {
      // write phase (scalar, swizzled)
#pragma unroll
      for (int nj = 0; nj < 4; ++nj)
#pragma unroll
        for (int r = 0; r < 4; ++r) {
          int row = (quad << 2) + r;
          int chunk = (nj * 4 + (fl >> 2)) ^ (row & 15);
          scr[row * 64 + chunk * 4 + (fl & 3)] = acc[mi][nj][r] * inv[nj];
        }
      LDS_FENCE();
      // read phase (vector) -> coalesced stores
#pragma unroll
      for (int p = 0; p < 4; ++p) {
        int row = (p << 2) + (lane >> 4);
        int c = lane & 15;
        int chunk = c ^ (row & 15);
        f32x4 v = *(const f32x4*)(scr + row * 64 + chunk * 4);
        *(f32x4*)(Co + (size_t)(rowg0 + mi * 16 + row) * NN + colbase + c * 4) = v;
      }
      MEM_FENCE();
    }
  }
}

// ---------------------------------------------------------------------------
// Copy curr_value into the second half of each batch's output channel block.
// ---------------------------------------------------------------------------
__global__ __launch_bounds__(256) void copy_curr(
    const float4* __restrict__ src, float4* __restrict__ dst) {
  size_t idx = (size_t)blockIdx.x * 256 + threadIdx.x;
  size_t b = idx >> 20;
  size_t r = idx & 1048575;
  dst[b * 2097152 + 1048576 + r] = src[idx];
}

// ---------------------------------------------------------------------------
extern "C" void kernel_launch(void* const* d_in, const int* in_sizes, int n_in,
                              void* d_out, int out_size, void* d_ws, size_t ws_size,
                              hipStream_t stream) {
  const float* prev_key   = (const float*)d_in[0];
  const float* prev_value = (const float*)d_in[1];
  const float* curr_key   = (const float*)d_in[2];
  const float* curr_value = (const float*)d_in[3];
  float* out = (float*)d_out;

  char* ws = (char*)d_ws;
  bf16* P     = (bf16*)(ws);                        // 256 MB [B][N][N]
  bf16* mk_t  = (bf16*)(ws + 268435456u);           //  64 MB [B][N][C]
  bf16* qk_t  = (bf16*)(ws + 335544320u);           //  64 MB [B][N][C]
  bf16* mo_b  = (bf16*)(ws + 402653184u);           //  64 MB [B][C][N]
  float* a_sq = (float*)(ws + 469762048u);          // 128 KB [B][N]
  float* rsum = a_sq + (size_t)BATCH * NN;          // 128 KB [B][N]

  hipMemsetAsync(a_sq, 0, 2ull * BATCH * NN * sizeof(float), stream);

  transpose_cast_v<true><<<dim3(NN / 64, CH / 64, BATCH), 256, 0, stream>>>(
      prev_key, mk_t, a_sq);
  transpose_cast_v<false><<<dim3(NN / 64, CH / 64, BATCH), 256, 0, stream>>>(
      curr_key, qk_t, nullptr);
  convert_cast<<<(size_t)BATCH * CH * NN / 4 / 256, 256, 0, stream>>>(
      (const float4*)prev_value, (bhalf4*)mo_b);

  // GEMM1: ab = qk_t * mk_t^T  (M=N=4096, K=1024), fused exp + rowsum.
  gemm_8p<CH, 0, 16><<<dim3(16 * 16 * BATCH), dim3(512), 0, stream>>>(
      qk_t, mk_t, P, nullptr, a_sq, rsum);

  // GEMM2: mem = mo * P^T  (M=1024, N=4096, K=4096), fused 1/rowsum.
  gemm_8p<NN, 1, 4><<<dim3(16 * 4 * BATCH), dim3(512), 0, stream>>>(
      mo_b, P, nullptr, out, nullptr, rsum);

  copy_curr<<<(size_t)BATCH * CH * NN / 4 / 256, 256, 0, stream>>>(
      (const float4*)curr_value, (float4*)out);
}

// Round 6
// 1265.664 us; speedup vs baseline: 1.3178x; 1.1310x over previous
//
#include <hip/hip_runtime.h>
#include <hip/hip_bf16.h>

// Problem constants (B, C, H, W) = (8, 1024, 64, 64); N = H*W = 4096.
#define BATCH 8
#define CH    1024
#define NN    4096

typedef __attribute__((ext_vector_type(8))) short bf16x8;   // 8 bf16 = 4 VGPRs
typedef __attribute__((ext_vector_type(4))) float f32x4;
using bf16 = __hip_bfloat16;

struct bhalf4 { bf16 x, y, z, w; };               // 8 bytes

__device__ __forceinline__ unsigned short f2bfu(float f) {
  bf16 h = __float2bfloat16(f);
  return *reinterpret_cast<unsigned short*>(&h);
}

// ---------------------------------------------------------------------------
// Vectorized transpose + cast: in [B][C][N] fp32 -> out [B][N][C] bf16.
// (unchanged from round-5 passing version)
// ---------------------------------------------------------------------------
template <bool ASQ>
__global__ __launch_bounds__(256) void transpose_cast_v(
    const float* __restrict__ in_all, bf16* __restrict__ out_all,
    float* __restrict__ asq_all) {
  int bz = blockIdx.z;
  const float* in = in_all + (size_t)bz * CH * NN;
  bf16* out = out_all + (size_t)bz * NN * CH;

  __shared__ float tile[64][65];
  __shared__ float sqb[16][64];

  int n0 = blockIdx.x * 64;
  int c0 = blockIdx.y * 64;
  int t = threadIdx.x;
  int nc = t & 15;
  int cr = t >> 4;

  float4 sq4 = make_float4(0.f, 0.f, 0.f, 0.f);
#pragma unroll
  for (int i = 0; i < 4; ++i) {
    int c = cr + i * 16;
    float4 v = *(const float4*)(in + (size_t)(c0 + c) * NN + n0 + nc * 4);
    tile[c][nc * 4 + 0] = v.x;
    tile[c][nc * 4 + 1] = v.y;
    tile[c][nc * 4 + 2] = v.z;
    tile[c][nc * 4 + 3] = v.w;
    if (ASQ) {
      sq4.x += v.x * v.x; sq4.y += v.y * v.y;
      sq4.z += v.z * v.z; sq4.w += v.w * v.w;
    }
  }
  if (ASQ) {
    sqb[cr][nc * 4 + 0] = sq4.x;
    sqb[cr][nc * 4 + 1] = sq4.y;
    sqb[cr][nc * 4 + 2] = sq4.z;
    sqb[cr][nc * 4 + 3] = sq4.w;
  }
  __syncthreads();
  if (ASQ && t < 64) {
    float s = 0.f;
#pragma unroll
    for (int i = 0; i < 16; ++i) s += sqb[i][t];
    atomicAdd(&asq_all[(size_t)bz * NN + n0 + t], s);
  }
  int cchunk = t & 7;
  int nb = t >> 3;
#pragma unroll
  for (int p = 0; p < 2; ++p) {
    int n = nb + p * 32;
    bf16x8 o;
#pragma unroll
    for (int j = 0; j < 8; ++j)
      o[j] = (short)f2bfu(tile[cchunk * 8 + j][n]);
    *(bf16x8*)(out + (size_t)(n0 + n) * CH + c0 + cchunk * 8) = o;
  }
}

// ---------------------------------------------------------------------------
// Plain cast: [B*C*N] fp32 -> bf16 flat.
// ---------------------------------------------------------------------------
__global__ __launch_bounds__(256) void convert_cast(
    const float4* __restrict__ in, bhalf4* __restrict__ out) {
  size_t i = (size_t)blockIdx.x * 256 + threadIdx.x;
  float4 v = in[i];
  bhalf4 o;
  o.x = __float2bfloat16(v.x);
  o.y = __float2bfloat16(v.y);
  o.z = __float2bfloat16(v.z);
  o.w = __float2bfloat16(v.w);
  out[i] = o;
}

// ---------------------------------------------------------------------------
// 128x128 / BK=32 / 3-buffer GEMM (C = A * B^T), inputs row-major [rows][K]
// bf16. 4 waves (2x2), per-wave 64x64 output. LDS only 48 KiB -> 3 blocks/CU
// (TLP replaces schedule finesse: co-resident blocks' barriers don't align,
// so one block's MFMA covers another's LDS/lgkm stall).
//
// One phase per K-tile (round-5 proven discipline):
//   {8 ds_read(t) ; stage(t+2) -> buf[(t+2)%3] ; barrier ; lgkmcnt(0) ;
//    sched_barrier ; 16 MFMA ; vmcnt(4) [tail: 0] ; barrier}
// Race audit (3-buffer, strictly simpler than the 2-buffer dance):
//   stage targets buf[(t+2)%3], which is NEITHER the buffer being read (t)
//   NOR the next (t+1). Its previous readers (tile t-1) drained their reads
//   at tile t-1's lgkmcnt(0), before t-1's trailing barrier -- the stage is
//   issued >= 1 barrier later. vmcnt(4) at end of tile t ensures t+1's 4
//   loads landed (leaves t+2's 4 in flight); when t+2>=NT nothing was
//   staged, so drain to 0.
//
// LDS swizzle for 32-elem (64 B) rows: chunk(0..3) ^= (row>>1)&3, applied
// on the pre-swizzled GLOBAL source (linear LDS dest, rule 21) and on the
// ds_read chunk. Bank enumeration for an 8-lane b128 group (quad q, rows
// r..r+7): bank_base = (fl&1)*16 + ((q^((fl>>1)&3))*4) -> 8 distinct 4-bank
// spans covering all 32 banks => conflict-free. (The naive (row&3) XOR
// 2-way-conflicts and halves LDS BW.)
//
// Tile->wg mapping: XCD swizzle (one batch per XCD) + L2 grouping: within a
// batch iterate bx-major over by-groups of GRP=8, so one B-panel (256 KB to
// 1 MB) is reused 8x back-to-back from L2 and the A-group stays L2-resident.
//
// MODE 0 (gemm1): e = exp((2*acc - asq[n])/32) -> P bf16 + rowsum atomics.
// MODE 1 (gemm2): acc / rowsum[n] -> fp32 out.
// ---------------------------------------------------------------------------
#define BARR() __builtin_amdgcn_s_barrier()
#define PRIO(x) __builtin_amdgcn_s_setprio(x)
#define LDS_FENCE() do {                                      \
    asm volatile("s_waitcnt lgkmcnt(0)" ::: "memory");        \
    __builtin_amdgcn_sched_barrier(0);                        \
  } while (0)
#define MEM_FENCE() do {                                      \
    asm volatile("" ::: "memory");                            \
    __builtin_amdgcn_sched_barrier(0);                        \
  } while (0)

__device__ __forceinline__ void gload16(const bf16* g, bf16* l) {
  __builtin_amdgcn_global_load_lds(
      (const __attribute__((address_space(1))) void*)g,
      (__attribute__((address_space(3))) void*)l, 16, 0, 0);
}

template <int K, int MODE, int TM, int TN>
__global__ __launch_bounds__(256, 3) void gemm_s3(
    const bf16* __restrict__ Aall, const bf16* __restrict__ Ball,
    bf16* __restrict__ Pall, float* __restrict__ Oall,
    const float* __restrict__ asq_all, float* __restrict__ rsum_all) {
  constexpr int NT = K / 32;
  constexpr int TPB = TM * TN;
  constexpr int NWG = TPB * BATCH;
  constexpr int GRP = 8;                 // by-group size for L2 reuse

  // XCD-bijective swizzle (NWG % 8 == 0): one batch per XCD chunk.
  int lid = blockIdx.x;
  int swz = (lid & 7) * (NWG >> 3) + (lid >> 3);
  int bz  = swz / TPB;
  int rem = swz - bz * TPB;
  // L2 grouping: bx-major sweep over by-groups of GRP.
  int g  = rem / (GRP * TN);
  int r2 = rem - g * (GRP * TN);
  int bx = r2 / GRP;
  int by = g * GRP + (r2 & (GRP - 1));

  const bf16* Ab = Aall + (size_t)bz * TM * 128 * K + (size_t)(by * 128) * K;
  const bf16* Bb = Ball + (size_t)bz * TN * 128 * K + (size_t)(bx * 128) * K;

  __shared__ bf16 As[3][128 * 32];       // 24 KiB
  __shared__ bf16 Bs[3][128 * 32];       // 24 KiB
  bf16* const AsB = &As[0][0];
  bf16* const BsB = &Bs[0][0];

  int tid = threadIdx.x;
  int wv = tid >> 6, lane = tid & 63;
  int fl = lane & 15, quad = lane >> 4;
  int wr = wv >> 1, wc = wv & 1;         // 2x2 waves, 64x64 each

  // Staging addresses: per tile each thread does 2x16B per matrix.
  // cid = p*256 + tid; row = cid>>2; lds chunk = cid&3;
  // global chunk = (cid&3) ^ ((row>>1)&3)  (inverse of read swizzle).
  int r0 = tid >> 2;
  int c0 = (tid & 3) ^ ((r0 >> 1) & 3);
  int r1 = (256 + tid) >> 2;
  int c1 = ((256 + tid) & 3) ^ ((r1 >> 1) & 3);
  const bf16* gA0 = Ab + (size_t)r0 * K + c0 * 8;
  const bf16* gA1 = Ab + (size_t)r1 * K + c1 * 8;
  const bf16* gB0 = Bb + (size_t)r0 * K + c0 * 8;
  const bf16* gB1 = Bb + (size_t)r1 * K + c1 * 8;
  int ls0 = wv * 512;                    // elems; lane*16B auto-added by DMA
  int ls1 = 2048 + wv * 512;

  // Fragment-read offsets (elems). row = (wr|wc)*64 + mi*16 + fl; bases are
  // multiples of 4 so (row>>1)&3 == ((fl>>1)&3) + 8*((..)) -- mi*16>>1 = mi*8
  // is 0 mod 4 and wr*64>>1 = wr*32 is 0 mod 4, so kq is lane-constant.
  int kq = (quad ^ ((fl >> 1) & 3)) * 8;
  int aoff = (wr * 64 + fl) * 32 + kq;
  int boff = (wc * 64 + fl) * 32 + kq;

  f32x4 acc[4][4] = {};

#define STAGE2() do {                                                         \
    bf16* da = AsB + sb * 4096;                                               \
    bf16* db = BsB + sb * 4096;                                               \
    gload16(gA0, da + ls0); gload16(gA1, da + ls1);                           \
    gload16(gB0, db + ls0); gload16(gB1, db + ls1);                           \
    gA0 += 32; gA1 += 32; gB0 += 32; gB1 += 32;                               \
  } while (0)

  // Prologue: stage tile 0 -> buf0, tile 1 -> buf1; drain tile 0 only.
  {
    int sb = 0; STAGE2();
    sb = 1; STAGE2();
  }
  asm volatile("s_waitcnt vmcnt(4)" ::: "memory");
  BARR();

  int cb = 0, sb = 2;
  for (int t = 0; t < NT; ++t) {
    const bf16* Ac = AsB + cb * 4096;
    const bf16* Bc = BsB + cb * 4096;
    bf16x8 aF[4], bF[4];
#pragma unroll
    for (int mi = 0; mi < 4; ++mi)
      aF[mi] = *(const bf16x8*)(Ac + aoff + mi * 512);
#pragma unroll
    for (int nj = 0; nj < 4; ++nj)
      bF[nj] = *(const bf16x8*)(Bc + boff + nj * 512);

    if (t + 2 < NT) STAGE2();

    BARR();
    asm volatile("s_waitcnt lgkmcnt(0)" ::: "memory");
    __builtin_amdgcn_sched_barrier(0);
    PRIO(1);
#pragma unroll
    for (int mi = 0; mi < 4; ++mi)
#pragma unroll
      for (int nj = 0; nj < 4; ++nj)
        acc[mi][nj] = __builtin_amdgcn_mfma_f32_16x16x32_bf16(
            aF[mi], bF[nj], acc[mi][nj], 0, 0, 0);
    PRIO(0);
    if (t + 2 < NT) {
      asm volatile("s_waitcnt vmcnt(4)" ::: "memory");
    } else {
      asm volatile("s_waitcnt vmcnt(0)" ::: "memory");
    }
    BARR();

    cb = (cb == 2) ? 0 : cb + 1;
    sb = (sb == 2) ? 0 : sb + 1;
  }
#undef STAGE2

  // All staging drained (tail vmcnt(0)) and reads consumed; sync before
  // reusing LDS as epilogue scratch.
  __syncthreads();

  // ---- Epilogue: wave-private 16x64 LDS transpose -> 16B stores ----
  int colbase = bx * 128 + wc * 64;
  int rowg0 = by * 128 + wr * 64;

  if constexpr (MODE == 0) {
    const float* asq = asq_all + (size_t)bz * NN;
    float* rsum = rsum_all + (size_t)bz * NN;
    bf16* P = Pall + (size_t)bz * NN * NN;
    short* scr = (short*)AsB + wv * 1024;   // 16x64 bf16 per wave

    float aq[4];
#pragma unroll
    for (int nj = 0; nj < 4; ++nj) aq[nj] = asq[colbase + nj * 16 + fl];

    float rs[4][4];
#pragma unroll
    for (int mi = 0; mi < 4; ++mi)
#pragma unroll
      for (int r = 0; r < 4; ++r) rs[mi][r] = 0.f;

#pragma unroll
    for (int mi = 0; mi < 4; ++mi) {
#pragma unroll
      for (int nj = 0; nj < 4; ++nj)
#pragma unroll
        for (int r = 0; r < 4; ++r) {
          int row = (quad << 2) + r;
          float e = __expf((2.f * acc[mi][nj][r] - aq[nj]) * 0.03125f);
          rs[mi][r] += e;
          int chunk = (nj * 2 + (fl >> 3)) ^ (row & 7);
          scr[row * 64 + chunk * 8 + (fl & 7)] = (short)f2bfu(e);
        }
      LDS_FENCE();
#pragma unroll
      for (int p = 0; p < 2; ++p) {
        int row = (p << 3) + (lane >> 3);
        int c = lane & 7;
        int chunk = c ^ (row & 7);
        bf16x8 v = *(const bf16x8*)(scr + row * 64 + chunk * 8);
        *(bf16x8*)(P + (size_t)(rowg0 + mi * 16 + row) * NN + colbase + c * 8) = v;
      }
      MEM_FENCE();
    }
#pragma unroll
    for (int mi = 0; mi < 4; ++mi)
#pragma unroll
      for (int r = 0; r < 4; ++r) {
        float v = rs[mi][r];
        v += __shfl_xor(v, 1);
        v += __shfl_xor(v, 2);
        v += __shfl_xor(v, 4);
        v += __shfl_xor(v, 8);
        if (fl == 0)
          atomicAdd(&rsum[rowg0 + mi * 16 + (quad << 2) + r], v);
      }
  } else {
    float* Co = Oall + (size_t)bz * 2 * CH * NN;     // first CV block
    const float* rsum = rsum_all + (size_t)bz * NN;
    float* scr = (float*)AsB + wv * 1024;            // 16x64 f32 per wave

    float inv[4];
#pragma unroll
    for (int nj = 0; nj < 4; ++nj) inv[nj] = 1.f / rsum[colbase + nj * 16 + fl];

#pragma unroll
    for (int mi = 0; mi < 4; ++mi) {
#pragma unroll
      for (int nj = 0; nj < 4; ++nj)
#pragma unroll
        for (int r = 0; r < 4; ++r) {
          int row = (quad << 2) + r;
          int chunk = (nj * 4 + (fl >> 2)) ^ (row & 15);
          scr[row * 64 + chunk * 4 + (fl & 3)] = acc[mi][nj][r] * inv[nj];
        }
      LDS_FENCE();
#pragma unroll
      for (int p = 0; p < 4; ++p) {
        int row = (p << 2) + (lane >> 4);
        int c = lane & 15;
        int chunk = c ^ (row & 15);
        f32x4 v = *(const f32x4*)(scr + row * 64 + chunk * 4);
        *(f32x4*)(Co + (size_t)(rowg0 + mi * 16 + row) * NN + colbase + c * 4) = v;
      }
      MEM_FENCE();
    }
  }
}

// ---------------------------------------------------------------------------
// Copy curr_value into the second half of each batch's output channel block.
// ---------------------------------------------------------------------------
__global__ __launch_bounds__(256) void copy_curr(
    const float4* __restrict__ src, float4* __restrict__ dst) {
  size_t idx = (size_t)blockIdx.x * 256 + threadIdx.x;
  size_t b = idx >> 20;
  size_t r = idx & 1048575;
  dst[b * 2097152 + 1048576 + r] = src[idx];
}

// ---------------------------------------------------------------------------
extern "C" void kernel_launch(void* const* d_in, const int* in_sizes, int n_in,
                              void* d_out, int out_size, void* d_ws, size_t ws_size,
                              hipStream_t stream) {
  const float* prev_key   = (const float*)d_in[0];
  const float* prev_value = (const float*)d_in[1];
  const float* curr_key   = (const float*)d_in[2];
  const float* curr_value = (const float*)d_in[3];
  float* out = (float*)d_out;

  char* ws = (char*)d_ws;
  bf16* P     = (bf16*)(ws);                        // 256 MB [B][N][N]
  bf16* mk_t  = (bf16*)(ws + 268435456u);           //  64 MB [B][N][C]
  bf16* qk_t  = (bf16*)(ws + 335544320u);           //  64 MB [B][N][C]
  bf16* mo_b  = (bf16*)(ws + 402653184u);           //  64 MB [B][C][N]
  float* a_sq = (float*)(ws + 469762048u);          // 128 KB [B][N]
  float* rsum = a_sq + (size_t)BATCH * NN;          // 128 KB [B][N]

  hipMemsetAsync(a_sq, 0, 2ull * BATCH * NN * sizeof(float), stream);

  transpose_cast_v<true><<<dim3(NN / 64, CH / 64, BATCH), 256, 0, stream>>>(
      prev_key, mk_t, a_sq);
  transpose_cast_v<false><<<dim3(NN / 64, CH / 64, BATCH), 256, 0, stream>>>(
      curr_key, qk_t, nullptr);
  convert_cast<<<(size_t)BATCH * CH * NN / 4 / 256, 256, 0, stream>>>(
      (const float4*)prev_value, (bhalf4*)mo_b);

  // GEMM1: ab = qk_t * mk_t^T  (M=N=4096, K=1024), fused exp + rowsum.
  gemm_s3<CH, 0, 32, 32><<<dim3(32 * 32 * BATCH), dim3(256), 0, stream>>>(
      qk_t, mk_t, P, nullptr, a_sq, rsum);

  // GEMM2: mem = mo * P^T  (M=1024, N=4096, K=4096), fused 1/rowsum.
  gemm_s3<NN, 1, 8, 32><<<dim3(8 * 32 * BATCH), dim3(256), 0, stream>>>(
      mo_b, P, nullptr, out, nullptr, rsum);

  copy_curr<<<(size_t)BATCH * CH * NN / 4 / 256, 256, 0, stream>>>(
      (const float4*)curr_value, (float4*)out);
}